// Round 3
// baseline (502.916 us; speedup 1.0000x reference)
//
#include <hip/hip_runtime.h>
#include <hip/hip_bf16.h>

typedef __attribute__((ext_vector_type(8))) short bf16x8;
typedef __attribute__((ext_vector_type(4))) float f32x4;

#define LOG2E 1.44269504088896340736f
#define RESCALE_THR 8.0f

__device__ __forceinline__ unsigned short f2bf(float f) {
  unsigned int u = __float_as_uint(f);
  u += 0x7FFFu + ((u >> 16) & 1u);   // RNE
  return (unsigned short)(u >> 16);
}

__device__ __forceinline__ unsigned int cvt_pk_bf16(float lo, float hi) {
  unsigned int r;
  asm("v_cvt_pk_bf16_f32 %0, %1, %2" : "=v"(r) : "v"(lo), "v"(hi));
  return r;
}

// ---------------- prep: h fp32 -> bf16 ----------------
__global__ void cvt_h_kernel(const float* __restrict__ src, unsigned short* __restrict__ dst, int n4) {
  int i = blockIdx.x * blockDim.x + threadIdx.x;
  if (i >= n4) return;
  float4 v = reinterpret_cast<const float4*>(src)[i];
  ushort4 o;
  o.x = f2bf(v.x); o.y = f2bf(v.y); o.z = f2bf(v.z); o.w = f2bf(v.w);
  reinterpret_cast<ushort4*>(dst)[i] = o;
}

// ---------------- prep: W [512][512] fp32 -> Wt bf16, Wt[o][i]=W[i][o], 3 mats ----------------
__global__ void cvt_wt_kernel(const float* __restrict__ Wq, const float* __restrict__ Wk,
                              const float* __restrict__ Wv, unsigned short* __restrict__ wt) {
  __shared__ float tile[32][33];
  const float* W = blockIdx.z == 0 ? Wq : (blockIdx.z == 1 ? Wk : Wv);
  int o0 = blockIdx.x * 32, i0 = blockIdx.y * 32;
  int c = threadIdx.x & 31, r4 = threadIdx.x >> 5;
  for (int rr = 0; rr < 32; rr += 8)
    tile[rr + r4][c] = W[(i0 + rr + r4) * 512 + o0 + c];
  __syncthreads();
  unsigned short* out = wt + blockIdx.z * 512 * 512;
  for (int rr = 0; rr < 32; rr += 8)
    out[(o0 + rr + r4) * 512 + i0 + c] = f2bf(tile[c][rr + r4]);
}

// ---------------- QKV projection GEMM: C = hb(4096x512) @ Wt^T + bias ----------------
__global__ __launch_bounds__(256) void qkv_gemm_kernel(
    const unsigned short* __restrict__ hb, const unsigned short* __restrict__ wt,
    const float* __restrict__ bq, const float* __restrict__ bk, const float* __restrict__ bv,
    unsigned short* __restrict__ qb, unsigned short* __restrict__ kb, unsigned short* __restrict__ vtb) {
  __shared__ unsigned short Asm[128 * 32];
  __shared__ unsigned short Bsm[128 * 32];
  const int mat = blockIdx.z;
  const unsigned short* Wm = wt + mat * 512 * 512;
  const float* bias = mat == 0 ? bq : (mat == 1 ? bk : bv);
  const int bm = blockIdx.y, bn = blockIdx.x;
  const int t = threadIdx.x;
  const int wid = t >> 6, lane = t & 63;
  const int wr = wid >> 1, wc = wid & 1;
  const int lg = lane >> 4, lr = lane & 15;

  f32x4 acc[4][4];
  for (int a = 0; a < 4; ++a)
    for (int b = 0; b < 4; ++b) acc[a][b] = {0.f, 0.f, 0.f, 0.f};

  for (int kk = 0; kk < 512; kk += 32) {
    __syncthreads();
    for (int u = 0; u < 2; ++u) {
      int idx = t + u * 256;
      int row = idx >> 2, seg = idx & 3;
      *reinterpret_cast<int4*>(&Asm[row * 32 + seg * 8]) =
          *reinterpret_cast<const int4*>(&hb[(bm * 128 + row) * 512 + kk + seg * 8]);
      *reinterpret_cast<int4*>(&Bsm[row * 32 + seg * 8]) =
          *reinterpret_cast<const int4*>(&Wm[(bn * 128 + row) * 512 + kk + seg * 8]);
    }
    __syncthreads();
    bf16x8 a[4], b[4];
    for (int f = 0; f < 4; ++f) {
      a[f] = *reinterpret_cast<const bf16x8*>(&Asm[(wr * 64 + f * 16 + lr) * 32 + lg * 8]);
      b[f] = *reinterpret_cast<const bf16x8*>(&Bsm[(wc * 64 + f * 16 + lr) * 32 + lg * 8]);
    }
    for (int fm = 0; fm < 4; ++fm)
      for (int fn = 0; fn < 4; ++fn)
        acc[fm][fn] = __builtin_amdgcn_mfma_f32_16x16x32_bf16(a[fm], b[fn], acc[fm][fn], 0, 0, 0);
  }

  for (int fm = 0; fm < 4; ++fm)
    for (int fn = 0; fn < 4; ++fn) {
      const int col = bn * 128 + wc * 64 + fn * 16 + lr;
      const float bval = bias[col];
      const int head = col >> 6, dh = col & 63;
      for (int r = 0; r < 4; ++r) {
        const int row = bm * 128 + wr * 64 + fm * 16 + lg * 4 + r;
        const unsigned short bf = f2bf(acc[fm][fn][r] + bval);
        if (mat == 0)      qb[(head * 4096 + row) * 64 + dh] = bf;
        else if (mat == 1) kb[(head * 4096 + row) * 64 + dh] = bf;
        else               vtb[(head * 64 + dh) * 4096 + row] = bf;
      }
    }
}

// ---------------- fused graph attention, split-j partials, NO barriers ----------------
// grid = (128 i-tiles, NSPLIT j-segments), 512 threads = 8 waves, wave = head.
// adj/mask read directly from global (L1/L2 shared across the 8 waves).
// P goes through a per-wave, rotation-swizzled LDS tile (conflict-free both ways).
template <int NSPLIT>
__global__ __launch_bounds__(512, 6) void attn_kernel(
    const unsigned short* __restrict__ qb, const unsigned short* __restrict__ kb,
    const unsigned short* __restrict__ vtb, const float* __restrict__ adj,
    const float* __restrict__ mask, float* __restrict__ pacc, float* __restrict__ pml) {
  constexpr int NT = 128 / NSPLIT;
  __shared__ __align__(16) unsigned short p_s[8][32][32];
  const int t = threadIdx.x;
  const int h = t >> 6, lane = t & 63;
  const int lg = lane >> 4, lr = lane & 15;
  const int i0 = blockIdx.x * 32;
  const int sp = blockIdx.y;
  const unsigned short* Qh = qb + h * 4096 * 64;
  const unsigned short* Kh = kb + h * 4096 * 64;
  const unsigned short* Vh = vtb + h * 64 * 4096;

  // Q fragments hoisted (B-operand of swapped QK^T)
  bf16x8 qf[2][2];
  for (int in_ = 0; in_ < 2; ++in_)
    for (int ks = 0; ks < 2; ++ks)
      qf[in_][ks] = *reinterpret_cast<const bf16x8*>(&Qh[(i0 + in_ * 16 + lr) * 64 + ks * 32 + lg * 8]);

  f32x4 acc[2][4];
  for (int fi = 0; fi < 2; ++fi)
    for (int fd = 0; fd < 4; ++fd) acc[fi][fd] = {0.f, 0.f, 0.f, 0.f};
  float m[2] = {-3e38f, -3e38f};
  float l[2] = {0.f, 0.f};

  for (int it = 0; it < NT; ++it) {
    const int j0 = (sp * NT + it) * 32;

    // adj/mask: direct global float4 loads (issued early)
    float4 av[2][2], mv[2][2];
    for (int in_ = 0; in_ < 2; ++in_)
      for (int jm = 0; jm < 2; ++jm) {
        const size_t off = (size_t)(i0 + in_ * 16 + lr) * 4096 + j0 + jm * 16 + lg * 4;
        av[in_][jm] = *reinterpret_cast<const float4*>(adj + off);
        mv[in_][jm] = *reinterpret_cast<const float4*>(mask + off);
      }

    // S^T = K_tile @ Q_tile^T
    f32x4 s[2][2];
    for (int jm = 0; jm < 2; ++jm)
      for (int in_ = 0; in_ < 2; ++in_) s[jm][in_] = {0.f, 0.f, 0.f, 0.f};
    for (int jm = 0; jm < 2; ++jm)
      for (int ks = 0; ks < 2; ++ks) {
        const bf16x8 kf = *reinterpret_cast<const bf16x8*>(&Kh[(j0 + jm * 16 + lr) * 64 + ks * 32 + lg * 8]);
        for (int in_ = 0; in_ < 2; ++in_)
          s[jm][in_] = __builtin_amdgcn_mfma_f32_16x16x32_bf16(kf, qf[in_][ks], s[jm][in_], 0, 0, 0);
      }

    // score = (adj*qk + mask) * (scale*log2e), in place; track per-row max
    float tm[2] = {-3e38f, -3e38f};
    for (int in_ = 0; in_ < 2; ++in_)
      for (int jm = 0; jm < 2; ++jm) {
        const float a0[4] = {av[in_][jm].x, av[in_][jm].y, av[in_][jm].z, av[in_][jm].w};
        const float m0[4] = {mv[in_][jm].x, mv[in_][jm].y, mv[in_][jm].z, mv[in_][jm].w};
        for (int r = 0; r < 4; ++r) {
          const float v = fmaf(a0[r], s[jm][in_][r], m0[r]) * (0.125f * LOG2E);
          s[jm][in_][r] = v;
          tm[in_] = fmaxf(tm[in_], v);
        }
      }
    for (int in_ = 0; in_ < 2; ++in_) {
      tm[in_] = fmaxf(tm[in_], __shfl_xor(tm[in_], 16));
      tm[in_] = fmaxf(tm[in_], __shfl_xor(tm[in_], 32));
    }

    // defer-max: rescale only when a row's max grows beyond the slack
    if (__any((tm[0] > m[0] + RESCALE_THR) || (tm[1] > m[1] + RESCALE_THR))) {
      const float mn0 = fmaxf(m[0], tm[0]);
      const float mn1 = fmaxf(m[1], tm[1]);
      const float f0 = exp2f(m[0] - mn0);
      const float f1 = exp2f(m[1] - mn1);
      l[0] *= f0; l[1] *= f1;
      m[0] = mn0; m[1] = mn1;
      const float ff[2] = {f0, f1};
      for (int fi = 0; fi < 2; ++fi)
        for (int r = 0; r < 4; ++r) {
          const float fr = __int_as_float(
              __builtin_amdgcn_ds_bpermute((lg * 4 + r) << 2, __float_as_int(ff[fi])));
          for (int fd = 0; fd < 4; ++fd) acc[fi][fd][r] *= fr;
        }
    }

    // p = exp2(sc - m); pack to bf16 pairs; store via rotation-swizzled per-wave LDS
    float ts[2] = {0.f, 0.f};
    for (int in_ = 0; in_ < 2; ++in_) {
      const int row = in_ * 16 + lr;
      for (int jm = 0; jm < 2; ++jm) {
        const float p0 = exp2f(s[jm][in_][0] - m[in_]);
        const float p1 = exp2f(s[jm][in_][1] - m[in_]);
        const float p2 = exp2f(s[jm][in_][2] - m[in_]);
        const float p3 = exp2f(s[jm][in_][3] - m[in_]);
        ts[in_] += (p0 + p1) + (p2 + p3);
        uint2 w;
        w.x = cvt_pk_bf16(p0, p1);
        w.y = cvt_pk_bf16(p2, p3);
        const int o = 2 * jm + (lg >> 1);                      // logical 16B unit
        const int colp = (((o + row) & 3) << 3) + ((lg & 1) << 2);  // swizzled ushort col
        *reinterpret_cast<uint2*>(&p_s[h][row][colp]) = w;
      }
    }
    for (int in_ = 0; in_ < 2; ++in_) {
      ts[in_] += __shfl_xor(ts[in_], 16);
      ts[in_] += __shfl_xor(ts[in_], 32);
      l[in_] += ts[in_];
    }

    // PV: A-frag from swizzled p_s, B-frag from V^T rows (per-wave; no barrier needed)
    bf16x8 pa[2];
    for (int fi = 0; fi < 2; ++fi) {
      const int row = fi * 16 + lr;
      const int colp = ((lg + row) & 3) << 3;
      pa[fi] = *reinterpret_cast<const bf16x8*>(&p_s[h][row][colp]);
    }
    for (int fd = 0; fd < 4; ++fd) {
      const bf16x8 vf = *reinterpret_cast<const bf16x8*>(&Vh[(size_t)(fd * 16 + lr) * 4096 + j0 + lg * 8]);
      for (int fi = 0; fi < 2; ++fi)
        acc[fi][fd] = __builtin_amdgcn_mfma_f32_16x16x32_bf16(pa[fi], vf, acc[fi][fd], 0, 0, 0);
    }
  }

  // epilogue: write unnormalized partials + (m,l)
  float* pa_base = pacc + ((size_t)sp * 4096 + i0) * 512;
  for (int fi = 0; fi < 2; ++fi)
    for (int fd = 0; fd < 4; ++fd)
      for (int r = 0; r < 4; ++r) {
        const int rowl = fi * 16 + lg * 4 + r;
        const int col = h * 64 + fd * 16 + lr;
        pa_base[rowl * 512 + col] = acc[fi][fd][r];
      }
  if (lane < 16) {
    for (int in_ = 0; in_ < 2; ++in_) {
      const int row = i0 + in_ * 16 + lane;
      float2 v; v.x = m[in_]; v.y = l[in_];
      reinterpret_cast<float2*>(pml)[((size_t)sp * 8 + h) * 4096 + row] = v;
    }
  }
}

// ---------------- combine splits ----------------
template <int NSPLIT>
__global__ __launch_bounds__(128) void combine_kernel(
    const float* __restrict__ pacc, const float* __restrict__ pml, float* __restrict__ out) {
  const int row = blockIdx.x;
  const int t = threadIdx.x;
  const int col = t * 4;
  const int head = col >> 6;

  float ms[NSPLIT], ls[NSPLIT];
  float M = -3e38f;
  for (int s = 0; s < NSPLIT; ++s) {
    const float2 v = reinterpret_cast<const float2*>(pml)[((size_t)s * 8 + head) * 4096 + row];
    ms[s] = v.x; ls[s] = v.y;
    M = fmaxf(M, v.x);
  }
  float denom = 0.f;
  float w[NSPLIT];
  for (int s = 0; s < NSPLIT; ++s) {
    w[s] = exp2f(ms[s] - M);
    denom += ls[s] * w[s];
  }
  const float inv = 1.0f / denom;
  float4 o = {0.f, 0.f, 0.f, 0.f};
  for (int s = 0; s < NSPLIT; ++s) {
    const float4 a = *reinterpret_cast<const float4*>(&pacc[((size_t)s * 4096 + row) * 512 + col]);
    o.x += a.x * w[s]; o.y += a.y * w[s]; o.z += a.z * w[s]; o.w += a.w * w[s];
  }
  o.x *= inv; o.y *= inv; o.z *= inv; o.w *= inv;
  *reinterpret_cast<float4*>(&out[(size_t)row * 512 + col]) = o;
}

extern "C" void kernel_launch(void* const* d_in, const int* in_sizes, int n_in,
                              void* d_out, int out_size, void* d_ws, size_t ws_size,
                              hipStream_t stream) {
  const float* h    = (const float*)d_in[0];
  const float* adj  = (const float*)d_in[1];
  const float* mask = (const float*)d_in[2];
  const float* Wq   = (const float*)d_in[3];
  const float* bq   = (const float*)d_in[4];
  const float* Wk   = (const float*)d_in[5];
  const float* bk   = (const float*)d_in[6];
  const float* Wv   = (const float*)d_in[7];
  const float* bv   = (const float*)d_in[8];
  float* out = (float*)d_out;

  char* ws = (char*)d_ws;
  unsigned short* hb = (unsigned short*)(ws);                    // 4 MiB
  unsigned short* wt = (unsigned short*)(ws + (4u  << 20));      // 1.5 MiB
  unsigned short* qb = (unsigned short*)(ws + (6u  << 20));      // 4 MiB [H][N][64]
  unsigned short* kb = (unsigned short*)(ws + (10u << 20));      // 4 MiB [H][N][64]
  unsigned short* vt = (unsigned short*)(ws + (14u << 20));      // 4 MiB [H][64][N]
  float* pacc = (float*)(ws + (20u << 20));                      // nsplit * 8 MiB

  const bool big = ws_size >= ((size_t)87 << 20);
  const int nsplit = big ? 8 : 4;
  float* pml = (float*)(ws + ((size_t)(20 + nsplit * 8) << 20)); // nsplit * 256 KiB

  cvt_h_kernel<<<dim3(2048), dim3(256), 0, stream>>>(h, hb, 4096 * 512 / 4);
  cvt_wt_kernel<<<dim3(16, 16, 3), dim3(256), 0, stream>>>(Wq, Wk, Wv, wt);
  qkv_gemm_kernel<<<dim3(4, 32, 3), dim3(256), 0, stream>>>(hb, wt, bq, bk, bv, qb, kb, vt);
  if (big) {
    attn_kernel<8><<<dim3(128, 8), dim3(512), 0, stream>>>(qb, kb, vt, adj, mask, pacc, pml);
    combine_kernel<8><<<dim3(4096), dim3(128), 0, stream>>>(pacc, pml, out);
  } else {
    attn_kernel<4><<<dim3(128, 4), dim3(512), 0, stream>>>(qb, kb, vt, adj, mask, pacc, pml);
    combine_kernel<4><<<dim3(4096), dim3(128), 0, stream>>>(pacc, pml, out);
  }
}

// Round 4
// 180.099 us; speedup vs baseline: 2.7924x; 2.7924x over previous
//
#include <hip/hip_runtime.h>
#include <hip/hip_bf16.h>

typedef __attribute__((ext_vector_type(8))) short bf16x8;
typedef __attribute__((ext_vector_type(4))) float f32x4;
typedef __attribute__((ext_vector_type(16))) float f32x16;

#define LOG2E 1.44269504088896340736f
#define RESCALE_THR 8.0f

__device__ __forceinline__ unsigned short f2bf(float f) {
  unsigned int u = __float_as_uint(f);
  u += 0x7FFFu + ((u >> 16) & 1u);   // RNE
  return (unsigned short)(u >> 16);
}

__device__ __forceinline__ unsigned int cvt_pk_bf16(float lo, float hi) {
  unsigned int r;
  asm("v_cvt_pk_bf16_f32 %0, %1, %2" : "=v"(r) : "v"(lo), "v"(hi));
  return r;
}

// ---------------- prep: h fp32 -> bf16 ----------------
__global__ void cvt_h_kernel(const float* __restrict__ src, unsigned short* __restrict__ dst, int n4) {
  int i = blockIdx.x * blockDim.x + threadIdx.x;
  if (i >= n4) return;
  float4 v = reinterpret_cast<const float4*>(src)[i];
  ushort4 o;
  o.x = f2bf(v.x); o.y = f2bf(v.y); o.z = f2bf(v.z); o.w = f2bf(v.w);
  reinterpret_cast<ushort4*>(dst)[i] = o;
}

// ---------------- prep: W [512][512] fp32 -> Wt bf16, Wt[o][i]=W[i][o], 3 mats ----------------
__global__ void cvt_wt_kernel(const float* __restrict__ Wq, const float* __restrict__ Wk,
                              const float* __restrict__ Wv, unsigned short* __restrict__ wt) {
  __shared__ float tile[32][33];
  const float* W = blockIdx.z == 0 ? Wq : (blockIdx.z == 1 ? Wk : Wv);
  int o0 = blockIdx.x * 32, i0 = blockIdx.y * 32;
  int c = threadIdx.x & 31, r4 = threadIdx.x >> 5;
  for (int rr = 0; rr < 32; rr += 8)
    tile[rr + r4][c] = W[(i0 + rr + r4) * 512 + o0 + c];
  __syncthreads();
  unsigned short* out = wt + blockIdx.z * 512 * 512;
  for (int rr = 0; rr < 32; rr += 8)
    out[(o0 + rr + r4) * 512 + i0 + c] = f2bf(tile[c][rr + r4]);
}

// ---------------- QKV projection GEMM: C = hb(4096x512) @ Wt^T + bias ----------------
__global__ __launch_bounds__(256) void qkv_gemm_kernel(
    const unsigned short* __restrict__ hb, const unsigned short* __restrict__ wt,
    const float* __restrict__ bq, const float* __restrict__ bk, const float* __restrict__ bv,
    unsigned short* __restrict__ qb, unsigned short* __restrict__ kb, unsigned short* __restrict__ vtb) {
  __shared__ unsigned short Asm[128 * 32];
  __shared__ unsigned short Bsm[128 * 32];
  const int mat = blockIdx.z;
  const unsigned short* Wm = wt + mat * 512 * 512;
  const float* bias = mat == 0 ? bq : (mat == 1 ? bk : bv);
  const int bm = blockIdx.y, bn = blockIdx.x;
  const int t = threadIdx.x;
  const int wid = t >> 6, lane = t & 63;
  const int wr = wid >> 1, wc = wid & 1;
  const int lg = lane >> 4, lr = lane & 15;

  f32x4 acc[4][4];
  for (int a = 0; a < 4; ++a)
    for (int b = 0; b < 4; ++b) acc[a][b] = {0.f, 0.f, 0.f, 0.f};

  for (int kk = 0; kk < 512; kk += 32) {
    __syncthreads();
    for (int u = 0; u < 2; ++u) {
      int idx = t + u * 256;
      int row = idx >> 2, seg = idx & 3;
      *reinterpret_cast<int4*>(&Asm[row * 32 + seg * 8]) =
          *reinterpret_cast<const int4*>(&hb[(bm * 128 + row) * 512 + kk + seg * 8]);
      *reinterpret_cast<int4*>(&Bsm[row * 32 + seg * 8]) =
          *reinterpret_cast<const int4*>(&Wm[(bn * 128 + row) * 512 + kk + seg * 8]);
    }
    __syncthreads();
    bf16x8 a[4], b[4];
    for (int f = 0; f < 4; ++f) {
      a[f] = *reinterpret_cast<const bf16x8*>(&Asm[(wr * 64 + f * 16 + lr) * 32 + lg * 8]);
      b[f] = *reinterpret_cast<const bf16x8*>(&Bsm[(wc * 64 + f * 16 + lr) * 32 + lg * 8]);
    }
    for (int fm = 0; fm < 4; ++fm)
      for (int fn = 0; fn < 4; ++fn)
        acc[fm][fn] = __builtin_amdgcn_mfma_f32_16x16x32_bf16(a[fm], b[fn], acc[fm][fn], 0, 0, 0);
  }

  for (int fm = 0; fm < 4; ++fm)
    for (int fn = 0; fn < 4; ++fn) {
      const int col = bn * 128 + wc * 64 + fn * 16 + lr;
      const float bval = bias[col];
      const int head = col >> 6, dh = col & 63;
      for (int r = 0; r < 4; ++r) {
        const int row = bm * 128 + wr * 64 + fm * 16 + lg * 4 + r;
        const unsigned short bf = f2bf(acc[fm][fn][r] + bval);
        if (mat == 0)      qb[(head * 4096 + row) * 64 + dh] = bf;
        else if (mat == 1) kb[(head * 4096 + row) * 64 + dh] = bf;
        else               vtb[(head * 64 + dh) * 4096 + row] = bf;
      }
    }
}

// ---------------- fused graph attention, 32x32 MFMA, split-j partials ----------------
// grid = (128 i-tiles, NSPLIT), 512 threads = 8 waves, wave = head.
// S^T = mfma_32x32x16(K, Q): lane col = i (lane&31), rows = j reg-indexed.
// Softmax is in-lane; P->A-frag built in-register (cvt_pk + shfl_xor(32) + select).
// adj/mask staged to LDS (pre-scaled), reg-staged double buffer, 1 barrier/iter.
template <int NSPLIT>
__global__ __launch_bounds__(512, 4) void attn_kernel(
    const unsigned short* __restrict__ qb, const unsigned short* __restrict__ kb,
    const unsigned short* __restrict__ vtb, const float* __restrict__ adj,
    const float* __restrict__ mask, float* __restrict__ pacc, float* __restrict__ pml) {
  constexpr int NT = 128 / NSPLIT;
  constexpr float CSC = 0.125f * LOG2E;
  __shared__ float adj_s[2][32][34];
  __shared__ float msk_s[2][32][34];
  const int t = threadIdx.x;
  const int h = t >> 6, lane = t & 63;
  const int il = lane & 31;
  const int hi = lane >> 5;
  const int i0 = blockIdx.x * 32;
  const int sp = blockIdx.y;
  const unsigned short* Qh = qb + h * 4096 * 64;
  const unsigned short* Kh = kb + h * 4096 * 64;
  const unsigned short* Vh = vtb + h * 64 * 4096;

  // Q B-fragments: qf[ks] holds Q[i0+il][ks*16 + hi*8 + e]
  bf16x8 qf[4];
#pragma unroll
  for (int ks = 0; ks < 4; ++ks)
    qf[ks] = *reinterpret_cast<const bf16x8*>(&Qh[(size_t)(i0 + il) * 64 + ks * 16 + hi * 8]);

  f32x16 acc0, acc1;
#pragma unroll
  for (int r = 0; r < 16; ++r) { acc0[r] = 0.f; acc1[r] = 0.f; }
  float m = -3e38f, l = 0.f;

  // staging role: t<256 -> adj, else mask; one float4 per thread per tile
  const int tt = t & 255;
  const int srow = tt >> 3, scu = tt & 7;
  const float* sbase = (t < 256 ? adj : mask) + (size_t)(i0 + srow) * 4096 + scu * 4;
  float* sd0 = (t < 256) ? &adj_s[0][srow][scu * 4] : &msk_s[0][srow][scu * 4];
  float* sd1 = (t < 256) ? &adj_s[1][srow][scu * 4] : &msk_s[1][srow][scu * 4];

  // prologue: stage tile 0 (pre-scaled)
  {
    const float4 g = *reinterpret_cast<const float4*>(sbase + (size_t)sp * NT * 32);
    float2 w0 = {g.x * CSC, g.y * CSC}, w1 = {g.z * CSC, g.w * CSC};
    reinterpret_cast<float2*>(sd0)[0] = w0;
    reinterpret_cast<float2*>(sd0)[1] = w1;
  }
  __syncthreads();

  for (int it = 0; it < NT; ++it) {
    const int j0 = (sp * NT + it) * 32;
    const int cur = it & 1;
    const bool havenext = (it + 1 < NT);
    float4 g;
    if (havenext) g = *reinterpret_cast<const float4*>(sbase + j0 + 32);  // T14 early issue

    // S^T block: A = K (rows j), B = Q (cols i)
    f32x16 sD;
#pragma unroll
    for (int r = 0; r < 16; ++r) sD[r] = 0.f;
#pragma unroll
    for (int ks = 0; ks < 4; ++ks) {
      const bf16x8 kf = *reinterpret_cast<const bf16x8*>(&Kh[(size_t)(j0 + il) * 64 + ks * 16 + hi * 8]);
      sD = __builtin_amdgcn_mfma_f32_32x32x16_bf16(kf, qf[ks], sD, 0, 0, 0);
    }

    // score_log2 = adj*CSC*qk + mask*CSC  (adj/mask pre-scaled in LDS)
    const float* ar = &adj_s[cur][il][4 * hi];
    const float* mr = &msk_s[cur][il][4 * hi];
    float sc[16];
#pragma unroll
    for (int q = 0; q < 4; ++q) {
      const float2 a0 = *reinterpret_cast<const float2*>(ar + 8 * q);
      const float2 a1 = *reinterpret_cast<const float2*>(ar + 8 * q + 2);
      const float2 b0 = *reinterpret_cast<const float2*>(mr + 8 * q);
      const float2 b1 = *reinterpret_cast<const float2*>(mr + 8 * q + 2);
      sc[4 * q + 0] = fmaf(a0.x, sD[4 * q + 0], b0.x);
      sc[4 * q + 1] = fmaf(a0.y, sD[4 * q + 1], b0.y);
      sc[4 * q + 2] = fmaf(a1.x, sD[4 * q + 2], b1.x);
      sc[4 * q + 3] = fmaf(a1.y, sD[4 * q + 3], b1.y);
    }

    // in-lane row max (16 values) + cross-half combine
    float x0 = fmaxf(sc[0], sc[1]),  x1 = fmaxf(sc[2], sc[3]);
    float x2 = fmaxf(sc[4], sc[5]),  x3 = fmaxf(sc[6], sc[7]);
    float x4 = fmaxf(sc[8], sc[9]),  x5 = fmaxf(sc[10], sc[11]);
    float x6 = fmaxf(sc[12], sc[13]), x7 = fmaxf(sc[14], sc[15]);
    x0 = fmaxf(x0, x1); x2 = fmaxf(x2, x3); x4 = fmaxf(x4, x5); x6 = fmaxf(x6, x7);
    x0 = fmaxf(x0, x2); x4 = fmaxf(x4, x6);
    float tmax = fmaxf(x0, x4);
    tmax = fmaxf(tmax, __shfl_xor(tmax, 32));

    // defer-max rescale
    if (__any(tmax > m + RESCALE_THR)) {
      const float mn = fmaxf(m, tmax);
      const float f = exp2f(m - mn);
      l *= f; m = mn;
#pragma unroll
      for (int r = 0; r < 16; ++r) {
        const int rb = ((r & 3) + 8 * (r >> 2)) * 4 + hi * 16;
        const float fr = __int_as_float(__builtin_amdgcn_ds_bpermute(rb, __float_as_int(f)));
        acc0[r] *= fr; acc1[r] *= fr;
      }
    }

    // p = exp2(sc - m); in-lane sum + cross-half
    float p[16];
#pragma unroll
    for (int r = 0; r < 16; ++r) p[r] = exp2f(sc[r] - m);
    float s0 = (p[0] + p[1]) + (p[2] + p[3]);
    float s1 = (p[4] + p[5]) + (p[6] + p[7]);
    float s2 = (p[8] + p[9]) + (p[10] + p[11]);
    float s3 = (p[12] + p[13]) + (p[14] + p[15]);
    float ts = (s0 + s1) + (s2 + s3);
    ts += __shfl_xor(ts, 32);
    l += ts;

    // build PV A-fragments in-register: pa[kk] covers j-local 16*kk..16*kk+15
    bf16x8 pa[2];
#pragma unroll
    for (int kk = 0; kk < 2; ++kk) {
      const unsigned X0 = cvt_pk_bf16(p[8 * kk + 0], p[8 * kk + 1]);
      const unsigned X1 = cvt_pk_bf16(p[8 * kk + 2], p[8 * kk + 3]);
      const unsigned Y0 = cvt_pk_bf16(p[8 * kk + 4], p[8 * kk + 5]);
      const unsigned Y1 = cvt_pk_bf16(p[8 * kk + 6], p[8 * kk + 7]);
      const unsigned tX0 = (unsigned)__shfl_xor((int)X0, 32);
      const unsigned tX1 = (unsigned)__shfl_xor((int)X1, 32);
      const unsigned tY0 = (unsigned)__shfl_xor((int)Y0, 32);
      const unsigned tY1 = (unsigned)__shfl_xor((int)Y1, 32);
      uint4 pw;
      pw.x = hi ? tY0 : X0;
      pw.y = hi ? tY1 : X1;
      pw.z = hi ? Y0 : tX0;
      pw.w = hi ? Y1 : tX1;
      pa[kk] = *reinterpret_cast<const bf16x8*>(&pw);
    }

    // PV: out(32i x 64d) += P(32x32) @ V(32x64); B from V^T rows, d = dc*32+il
#pragma unroll
    for (int kk = 0; kk < 2; ++kk) {
      const bf16x8 v0 = *reinterpret_cast<const bf16x8*>(&Vh[(size_t)il * 4096 + j0 + kk * 16 + hi * 8]);
      const bf16x8 v1 = *reinterpret_cast<const bf16x8*>(&Vh[(size_t)(32 + il) * 4096 + j0 + kk * 16 + hi * 8]);
      acc0 = __builtin_amdgcn_mfma_f32_32x32x16_bf16(pa[kk], v0, acc0, 0, 0, 0);
      acc1 = __builtin_amdgcn_mfma_f32_32x32x16_bf16(pa[kk], v1, acc1, 0, 0, 0);
    }

    // late LDS write of next tile (pre-scaled), single barrier
    if (havenext) {
      float* d = (cur ^ 1) ? sd1 : sd0;
      float2 w0 = {g.x * CSC, g.y * CSC}, w1 = {g.z * CSC, g.w * CSC};
      reinterpret_cast<float2*>(d)[0] = w0;
      reinterpret_cast<float2*>(d)[1] = w1;
    }
    __syncthreads();
  }

  // epilogue: unnormalized partials + (m,l)
  float* pb = pacc + ((size_t)sp * 4096 + i0) * 512 + h * 64;
#pragma unroll
  for (int r = 0; r < 16; ++r) {
    const int rowr = (r & 3) + 8 * (r >> 2) + 4 * hi;
    pb[(size_t)rowr * 512 + il] = acc0[r];
    pb[(size_t)rowr * 512 + 32 + il] = acc1[r];
  }
  if (lane < 32) {
    float2 v; v.x = m; v.y = l;
    reinterpret_cast<float2*>(pml)[((size_t)sp * 8 + h) * 4096 + i0 + lane] = v;
  }
}

// ---------------- combine splits ----------------
template <int NSPLIT>
__global__ __launch_bounds__(128) void combine_kernel(
    const float* __restrict__ pacc, const float* __restrict__ pml, float* __restrict__ out) {
  const int row = blockIdx.x;
  const int t = threadIdx.x;
  const int col = t * 4;
  const int head = col >> 6;

  float ms[NSPLIT], ls[NSPLIT];
  float M = -3e38f;
  for (int s = 0; s < NSPLIT; ++s) {
    const float2 v = reinterpret_cast<const float2*>(pml)[((size_t)s * 8 + head) * 4096 + row];
    ms[s] = v.x; ls[s] = v.y;
    M = fmaxf(M, v.x);
  }
  float denom = 0.f;
  float w[NSPLIT];
  for (int s = 0; s < NSPLIT; ++s) {
    w[s] = exp2f(ms[s] - M);
    denom += ls[s] * w[s];
  }
  const float inv = 1.0f / denom;
  float4 o = {0.f, 0.f, 0.f, 0.f};
  for (int s = 0; s < NSPLIT; ++s) {
    const float4 a = *reinterpret_cast<const float4*>(&pacc[((size_t)s * 4096 + row) * 512 + col]);
    o.x += a.x * w[s]; o.y += a.y * w[s]; o.z += a.z * w[s]; o.w += a.w * w[s];
  }
  o.x *= inv; o.y *= inv; o.z *= inv; o.w *= inv;
  *reinterpret_cast<float4*>(&out[(size_t)row * 512 + col]) = o;
}

extern "C" void kernel_launch(void* const* d_in, const int* in_sizes, int n_in,
                              void* d_out, int out_size, void* d_ws, size_t ws_size,
                              hipStream_t stream) {
  const float* h    = (const float*)d_in[0];
  const float* adj  = (const float*)d_in[1];
  const float* mask = (const float*)d_in[2];
  const float* Wq   = (const float*)d_in[3];
  const float* bq   = (const float*)d_in[4];
  const float* Wk   = (const float*)d_in[5];
  const float* bk   = (const float*)d_in[6];
  const float* Wv   = (const float*)d_in[7];
  const float* bv   = (const float*)d_in[8];
  float* out = (float*)d_out;

  char* ws = (char*)d_ws;
  unsigned short* hb = (unsigned short*)(ws);                    // 4 MiB
  unsigned short* wt = (unsigned short*)(ws + (4u  << 20));      // 1.5 MiB
  unsigned short* qb = (unsigned short*)(ws + (6u  << 20));      // 4 MiB [H][N][64]
  unsigned short* kb = (unsigned short*)(ws + (10u << 20));      // 4 MiB [H][N][64]
  unsigned short* vt = (unsigned short*)(ws + (14u << 20));      // 4 MiB [H][64][N]
  float* pacc = (float*)(ws + (20u << 20));                      // 32 MiB [4][4096][512]
  float* pml  = (float*)(ws + (52u << 20));                      // 1 MiB  [4][8][4096] float2

  cvt_h_kernel<<<dim3(2048), dim3(256), 0, stream>>>(h, hb, 4096 * 512 / 4);
  cvt_wt_kernel<<<dim3(16, 16, 3), dim3(256), 0, stream>>>(Wq, Wk, Wv, wt);
  qkv_gemm_kernel<<<dim3(4, 32, 3), dim3(256), 0, stream>>>(hb, wt, bq, bk, bv, qb, kb, vt);
  attn_kernel<4><<<dim3(128, 4), dim3(512), 0, stream>>>(qb, kb, vt, adj, mask, pacc, pml);
  combine_kernel<4><<<dim3(4096), dim3(128), 0, stream>>>(pacc, pml, out);
}